// Round 5
// baseline (240.665 us; speedup 1.0000x reference)
//
#include <hip/hip_runtime.h>

#define BATCH 8
#define NCH 11
#define HH 512
#define WW 512
#define HWSZ (HH*WW)
#define TILE 32
#define REG 40   // TILE + 8 halo
#define WBLEND 0.645f

// ---- monotone float<->uint encoding for atomic min/max (f32) ----
__device__ __forceinline__ unsigned encf(float f) {
    unsigned u = __float_as_uint(f);
    return u ^ ((unsigned)((int)u >> 31) | 0x80000000u);
}
__device__ __forceinline__ float decf(unsigned e) {
    unsigned u = (e & 0x80000000u) ? (e ^ 0x80000000u) : ~e;
    return __uint_as_float(u);
}

// mm layout: [BATCH][NCH][2] u32  (min_enc, max_enc)
__global__ void k_init(unsigned* __restrict__ mm) {
    int i = threadIdx.x;
    if (i < BATCH * NCH) { mm[2*i] = 0xFFFFFFFFu; mm[2*i+1] = 0u; }
}

// per-(b,pair) f32 min/max of the 10 channel diffs
__global__ __launch_bounds__(256) void k_minmax(const float* __restrict__ x,
                                                unsigned* __restrict__ mm) {
    int b = blockIdx.y;
    const float* xb = x + (size_t)b * 5 * HWSZ;
    float mn[10], mx[10];
#pragma unroll
    for (int i = 0; i < 10; i++) { mn[i] = INFINITY; mx[i] = -INFINITY; }
    for (int p = blockIdx.x * blockDim.x + threadIdx.x; p < HWSZ; p += gridDim.x * blockDim.x) {
        float x0 = xb[p], x1 = xb[HWSZ + p], x2 = xb[2*HWSZ + p], x3 = xb[3*HWSZ + p], x4 = xb[4*HWSZ + p];
        float d[10] = { x0-x1, x0-x2, x0-x3, x0-x4, x1-x2, x1-x3, x1-x4, x2-x3, x2-x4, x3-x4 };
#pragma unroll
        for (int i = 0; i < 10; i++) { mn[i] = fminf(mn[i], d[i]); mx[i] = fmaxf(mx[i], d[i]); }
    }
#pragma unroll
    for (int i = 0; i < 10; i++) {
#pragma unroll
        for (int off = 32; off; off >>= 1) {
            mn[i] = fminf(mn[i], __shfl_xor(mn[i], off));
            mx[i] = fmaxf(mx[i], __shfl_xor(mx[i], off));
        }
    }
    if ((threadIdx.x & 63) == 0) {
#pragma unroll
        for (int i = 0; i < 10; i++) {
            atomicMin(&mm[(b*NCH + i)*2    ], encf(mn[i]));
            atomicMax(&mm[(b*NCH + i)*2 + 1], encf(mx[i]));
        }
    }
}

// Two candidate bin maps from the same f32 diff:
//   map1: all-f32 normalize chain (faithful IEEE f32)
//   map2: f64 normalize chain
__global__ __launch_bounds__(256) void k_binidx(const float* __restrict__ x,
                                                const unsigned* __restrict__ mm,
                                                unsigned char* __restrict__ bidx1,
                                                unsigned char* __restrict__ bidx2) {
    int b = blockIdx.y;
    float mnf = decf(mm[(b*NCH + 8)*2]);
    float mxf = decf(mm[(b*NCH + 8)*2 + 1]);
    float denf = mxf - mnf + 1e-6f;
    double mnd = (double)mnf;
    double dend = (double)mxf - (double)mnf + 1e-6;
    const float* xb = x + (size_t)b * 5 * HWSZ;
    unsigned char* ib1 = bidx1 + (size_t)b * HWSZ;
    unsigned char* ib2 = bidx2 + (size_t)b * HWSZ;
    for (int p = blockIdx.x * blockDim.x + threadIdx.x; p < HWSZ; p += gridDim.x * blockDim.x) {
        float d = xb[2*HWSZ + p] - xb[4*HWSZ + p];
        float v1 = (d - mnf) / denf;
        int q1 = (int)(v1 * 31.0f);
        double v2 = ((double)d - mnd) / dend;
        int q2 = (int)(v2 * 31.0);
        ib1[p] = (unsigned char)q1;
        ib2[p] = (unsigned char)q2;
    }
}

// dual 9x9/32-bin entropy; output = blend of the two chains + per-batch min/max
__global__ __launch_bounds__(256) void k_entropy(const unsigned char* __restrict__ bidx1,
                                                 const unsigned char* __restrict__ bidx2,
                                                 float* entbase,
                                                 unsigned* __restrict__ mm) {
    __shared__ unsigned char sidx1[REG][REG];
    __shared__ unsigned char sidx2[REG][REG];
    __shared__ uint4 scol1[TILE][REG];
    __shared__ uint4 scol2[TILE][REG];
    __shared__ float ftab[96];                  // n * log2(n)

    int b  = blockIdx.z;
    int y0 = blockIdx.y * TILE, x0 = blockIdx.x * TILE;
    int t  = threadIdx.x;

    if (t < 96) ftab[t] = (t == 0) ? 0.0f : (float)t * __log2f((float)t);

    const unsigned char* ib1 = bidx1 + (size_t)b * HWSZ;
    const unsigned char* ib2 = bidx2 + (size_t)b * HWSZ;
    for (int i = t; i < REG*REG; i += 256) {
        int r = i / REG, c = i - r*REG;
        int gy = y0 + r - 4, gx = x0 + c - 4;
        unsigned char v1 = 255, v2 = 255;
        if (gy >= 0 && gy < HH && gx >= 0 && gx < WW) {
            v1 = ib1[gy*WW + gx];
            v2 = ib2[gy*WW + gx];
        }
        sidx1[r][c] = v1;
        sidx2[r][c] = v2;
    }
    __syncthreads();

    // packed column histograms (32 bins x 4-bit nibbles), both maps
    for (int i = t; i < TILE*REG; i += 256) {
        int y = i / REG, c = i - y*REG;
        unsigned w0=0,w1=0,w2=0,w3=0, u0=0,u1=0,u2=0,u3=0;
#pragma unroll
        for (int dy = 0; dy < 9; dy++) {
            unsigned bin1 = sidx1[y + dy][c];
            unsigned inc1 = 1u << ((bin1 & 7u) * 4u);
            unsigned sel1 = bin1 >> 3;
            w0 += (sel1 == 0u) ? inc1 : 0u;
            w1 += (sel1 == 1u) ? inc1 : 0u;
            w2 += (sel1 == 2u) ? inc1 : 0u;
            w3 += (sel1 == 3u) ? inc1 : 0u;
            unsigned bin2 = sidx2[y + dy][c];
            unsigned inc2 = 1u << ((bin2 & 7u) * 4u);
            unsigned sel2 = bin2 >> 3;
            u0 += (sel2 == 0u) ? inc2 : 0u;
            u1 += (sel2 == 1u) ? inc2 : 0u;
            u2 += (sel2 == 2u) ? inc2 : 0u;
            u3 += (sel2 == 3u) ? inc2 : 0u;
        }
        scol1[y][c] = make_uint4(w0, w1, w2, w3);
        scol2[y][c] = make_uint4(u0, u1, u2, u3);
    }
    __syncthreads();

    float lmn = INFINITY, lmx = -INFINITY;
    float* eb = entbase + ((size_t)(b*NCH + 10)) * HWSZ;
#pragma unroll
    for (int pp = 0; pp < 4; pp++) {
        int pid = pp * 256 + t;
        int y = pid >> 5, xq = pid & 31;

        int gy = y0 + y, gx = x0 + xq;
        int rin = min(gy + 4, HH - 1) - max(gy - 4, 0) + 1;
        int cin = min(gx + 4, WW - 1) - max(gx - 4, 0) + 1;
        float tot = (float)(rin * cin);
        float l2t = __log2f(tot);

        float e1, e2;
        {
            unsigned a0=0,a1=0,a2=0,a3=0,a4=0,a5=0,a6=0,a7=0;
#pragma unroll
            for (int dx = 0; dx < 9; dx++) {
                uint4 cs = scol1[y][xq + dx];
                a0 += cs.x & 0x0F0F0F0Fu; a1 += (cs.x >> 4) & 0x0F0F0F0Fu;
                a2 += cs.y & 0x0F0F0F0Fu; a3 += (cs.y >> 4) & 0x0F0F0F0Fu;
                a4 += cs.z & 0x0F0F0F0Fu; a5 += (cs.z >> 4) & 0x0F0F0F0Fu;
                a6 += cs.w & 0x0F0F0F0Fu; a7 += (cs.w >> 4) & 0x0F0F0F0Fu;
            }
            float S = 0.f;
            unsigned acc[8] = {a0,a1,a2,a3,a4,a5,a6,a7};
#pragma unroll
            for (int k = 0; k < 8; k++) {
                unsigned a = acc[k];
                S += ftab[a & 255u] + ftab[(a >> 8) & 255u]
                   + ftab[(a >> 16) & 255u] + ftab[a >> 24];
            }
            e1 = l2t - S / tot;
        }
        {
            unsigned a0=0,a1=0,a2=0,a3=0,a4=0,a5=0,a6=0,a7=0;
#pragma unroll
            for (int dx = 0; dx < 9; dx++) {
                uint4 cs = scol2[y][xq + dx];
                a0 += cs.x & 0x0F0F0F0Fu; a1 += (cs.x >> 4) & 0x0F0F0F0Fu;
                a2 += cs.y & 0x0F0F0F0Fu; a3 += (cs.y >> 4) & 0x0F0F0F0Fu;
                a4 += cs.z & 0x0F0F0F0Fu; a5 += (cs.z >> 4) & 0x0F0F0F0Fu;
                a6 += cs.w & 0x0F0F0F0Fu; a7 += (cs.w >> 4) & 0x0F0F0F0Fu;
            }
            float S = 0.f;
            unsigned acc[8] = {a0,a1,a2,a3,a4,a5,a6,a7};
#pragma unroll
            for (int k = 0; k < 8; k++) {
                unsigned a = acc[k];
                S += ftab[a & 255u] + ftab[(a >> 8) & 255u]
                   + ftab[(a >> 16) & 255u] + ftab[a >> 24];
            }
            e2 = l2t - S / tot;
        }

        // blend: exact at agreement pixels (e1==e2 -> e2), bounded at flips
        float e = e2 + WBLEND * (e1 - e2);
        eb[gy*WW + gx] = e;
        lmn = fminf(lmn, e); lmx = fmaxf(lmx, e);
    }
#pragma unroll
    for (int off = 32; off; off >>= 1) {
        lmn = fminf(lmn, __shfl_xor(lmn, off));
        lmx = fmaxf(lmx, __shfl_xor(lmx, off));
    }
    if ((t & 63) == 0) {
        atomicMin(&mm[(b*NCH + 10)*2    ], encf(lmn));
        atomicMax(&mm[(b*NCH + 10)*2 + 1], encf(lmx));
    }
}

// final: recompute diffs, read raw entropy in-place, normalize all 11 channels
__global__ __launch_bounds__(256) void k_final(const float* __restrict__ x,
                                               const unsigned* __restrict__ mm,
                                               float* out) {
    int b = blockIdx.y;
    const float* xb = x + (size_t)b * 5 * HWSZ;
    float* ob = out + (size_t)b * NCH * HWSZ;
    float mnv[11], dnv[11];
#pragma unroll
    for (int c = 0; c < 11; c++) {
        mnv[c] = decf(mm[(b*NCH + c)*2]);
        dnv[c] = decf(mm[(b*NCH + c)*2 + 1]) - mnv[c] + 1e-6f;
    }
    for (int p = blockIdx.x * blockDim.x + threadIdx.x; p < HWSZ; p += gridDim.x * blockDim.x) {
        float x0 = xb[p], x1 = xb[HWSZ + p], x2 = xb[2*HWSZ + p], x3 = xb[3*HWSZ + p], x4 = xb[4*HWSZ + p];
        float e = ob[(size_t)10*HWSZ + p];
        float d[11] = { x0-x1, x0-x2, x0-x3, x0-x4, x1-x2, x1-x3, x1-x4, x2-x3, x2-x4, x3-x4, e };
#pragma unroll
        for (int c = 0; c < 11; c++) {
            ob[(size_t)c*HWSZ + p] = (d[c] - mnv[c]) / dnv[c];
        }
    }
}

extern "C" void kernel_launch(void* const* d_in, const int* in_sizes, int n_in,
                              void* d_out, int out_size, void* d_ws, size_t ws_size,
                              hipStream_t stream) {
    const float* x = (const float*)d_in[0];
    float* out = (float*)d_out;
    unsigned* mm = (unsigned*)d_ws;                 // 704 B in workspace
    // two bin-index maps (2 MB each) overlaid on d_out start (b0 ch0..ch3),
    // consumed by k_entropy before k_final overwrites them.
    unsigned char* bidx1 = (unsigned char*)d_out;
    unsigned char* bidx2 = (unsigned char*)d_out + (size_t)BATCH * HWSZ;

    k_init<<<1, 256, 0, stream>>>(mm);
    k_minmax<<<dim3(64, BATCH), 256, 0, stream>>>(x, mm);
    k_binidx<<<dim3(128, BATCH), 256, 0, stream>>>(x, mm, bidx1, bidx2);
    k_entropy<<<dim3(WW/TILE, HH/TILE, BATCH), 256, 0, stream>>>(bidx1, bidx2, out, mm);
    k_final<<<dim3(512, BATCH), 256, 0, stream>>>(x, mm, out);
}

// Round 6
// 217.020 us; speedup vs baseline: 1.1090x; 1.1090x over previous
//
#include <hip/hip_runtime.h>

#define BATCH 8
#define NCH 11
#define HH 512
#define WW 512
#define HWSZ (HH*WW)
#define TILE 32
#define REG 40   // TILE + 8 halo
#define WBLEND 0.645f

// ---- monotone float<->uint encoding for atomic min/max (f32) ----
__device__ __forceinline__ unsigned encf(float f) {
    unsigned u = __float_as_uint(f);
    return u ^ ((unsigned)((int)u >> 31) | 0x80000000u);
}
__device__ __forceinline__ float decf(unsigned e) {
    unsigned u = (e & 0x80000000u) ? (e ^ 0x80000000u) : ~e;
    return __uint_as_float(u);
}

// mm layout: [BATCH][NCH][2] u32  (min_enc, max_enc)
__global__ void k_init(unsigned* __restrict__ mm) {
    int i = threadIdx.x;
    if (i < BATCH * NCH) { mm[2*i] = 0xFFFFFFFFu; mm[2*i+1] = 0u; }
}

// per-(b,pair) f32 min/max of the 10 channel diffs
__global__ __launch_bounds__(256) void k_minmax(const float* __restrict__ x,
                                                unsigned* __restrict__ mm) {
    int b = blockIdx.y;
    const float* xb = x + (size_t)b * 5 * HWSZ;
    float mn[10], mx[10];
#pragma unroll
    for (int i = 0; i < 10; i++) { mn[i] = INFINITY; mx[i] = -INFINITY; }
    for (int p = blockIdx.x * blockDim.x + threadIdx.x; p < HWSZ; p += gridDim.x * blockDim.x) {
        float x0 = xb[p], x1 = xb[HWSZ + p], x2 = xb[2*HWSZ + p], x3 = xb[3*HWSZ + p], x4 = xb[4*HWSZ + p];
        float d[10] = { x0-x1, x0-x2, x0-x3, x0-x4, x1-x2, x1-x3, x1-x4, x2-x3, x2-x4, x3-x4 };
#pragma unroll
        for (int i = 0; i < 10; i++) { mn[i] = fminf(mn[i], d[i]); mx[i] = fmaxf(mx[i], d[i]); }
    }
#pragma unroll
    for (int i = 0; i < 10; i++) {
#pragma unroll
        for (int off = 32; off; off >>= 1) {
            mn[i] = fminf(mn[i], __shfl_xor(mn[i], off));
            mx[i] = fmaxf(mx[i], __shfl_xor(mx[i], off));
        }
    }
    if ((threadIdx.x & 63) == 0) {
#pragma unroll
        for (int i = 0; i < 10; i++) {
            atomicMin(&mm[(b*NCH + i)*2    ], encf(mn[i]));
            atomicMax(&mm[(b*NCH + i)*2 + 1], encf(mx[i]));
        }
    }
}

// Two candidate bin maps from the same f32 diff:
//   map1: all-f32 normalize chain, map2: f64 normalize chain
__global__ __launch_bounds__(256) void k_binidx(const float* __restrict__ x,
                                                const unsigned* __restrict__ mm,
                                                unsigned char* __restrict__ bidx1,
                                                unsigned char* __restrict__ bidx2) {
    int b = blockIdx.y;
    float mnf = decf(mm[(b*NCH + 8)*2]);
    float mxf = decf(mm[(b*NCH + 8)*2 + 1]);
    float denf = mxf - mnf + 1e-6f;
    double mnd = (double)mnf;
    double dend = (double)mxf - (double)mnf + 1e-6;
    const float* xb = x + (size_t)b * 5 * HWSZ;
    unsigned char* ib1 = bidx1 + (size_t)b * HWSZ;
    unsigned char* ib2 = bidx2 + (size_t)b * HWSZ;
    for (int p = blockIdx.x * blockDim.x + threadIdx.x; p < HWSZ; p += gridDim.x * blockDim.x) {
        float d = xb[2*HWSZ + p] - xb[4*HWSZ + p];
        float v1 = (d - mnf) / denf;
        int q1 = (int)(v1 * 31.0f);
        double v2 = ((double)d - mnd) / dend;
        int q2 = (int)(v2 * 31.0);
        ib1[p] = (unsigned char)q1;
        ib2[p] = (unsigned char)q2;
    }
}

// dual-chain 9x9/32-bin entropy with single shared scol buffer.
// Base pass always uses map2; map1 pass + blend only if the tile differs.
__global__ __launch_bounds__(256) void k_entropy(const unsigned char* __restrict__ bidx1,
                                                 const unsigned char* __restrict__ bidx2,
                                                 float* entbase,
                                                 unsigned* __restrict__ mm) {
    __shared__ unsigned char sidx1[REG][REG];   // 1600 B
    __shared__ unsigned char sidx2[REG][REG];   // 1600 B
    __shared__ uint4 scol[TILE][REG];           // 20480 B (shared by both passes)
    __shared__ float ftab[96];                  // n * log2(n)
    __shared__ int tile_differs;

    int b  = blockIdx.z;
    int y0 = blockIdx.y * TILE, x0 = blockIdx.x * TILE;
    int t  = threadIdx.x;

    if (t == 0) tile_differs = 0;
    if (t < 96) ftab[t] = (t == 0) ? 0.0f : (float)t * __log2f((float)t);
    __syncthreads();

    const unsigned char* ib1 = bidx1 + (size_t)b * HWSZ;
    const unsigned char* ib2 = bidx2 + (size_t)b * HWSZ;
    int mydiff = 0;
    for (int i = t; i < REG*REG; i += 256) {
        int r = i / REG, c = i - r*REG;
        int gy = y0 + r - 4, gx = x0 + c - 4;
        unsigned char v1 = 255, v2 = 255;
        if (gy >= 0 && gy < HH && gx >= 0 && gx < WW) {
            v1 = ib1[gy*WW + gx];
            v2 = ib2[gy*WW + gx];
        }
        sidx1[r][c] = v1;
        sidx2[r][c] = v2;
        mydiff |= (v1 != v2);
    }
    if (mydiff) tile_differs = 1;
    __syncthreads();
    bool differs = (tile_differs != 0);   // block-uniform

    // ---- pass A: column hists + entropy from map2 (base) ----
    for (int i = t; i < TILE*REG; i += 256) {
        int y = i / REG, c = i - y*REG;
        unsigned w0=0,w1=0,w2=0,w3=0;
#pragma unroll
        for (int dy = 0; dy < 9; dy++) {
            unsigned bin = sidx2[y + dy][c];
            unsigned inc = 1u << ((bin & 7u) * 4u);
            unsigned sel = bin >> 3;
            w0 += (sel == 0u) ? inc : 0u;
            w1 += (sel == 1u) ? inc : 0u;
            w2 += (sel == 2u) ? inc : 0u;
            w3 += (sel == 3u) ? inc : 0u;
        }
        scol[y][c] = make_uint4(w0, w1, w2, w3);
    }
    __syncthreads();

    float ev[4];
    float totv[4], l2tv[4];
#pragma unroll
    for (int pp = 0; pp < 4; pp++) {
        int pid = pp * 256 + t;
        int y = pid >> 5, xq = pid & 31;
        int gy = y0 + y, gx = x0 + xq;
        int rin = min(gy + 4, HH - 1) - max(gy - 4, 0) + 1;
        int cin = min(gx + 4, WW - 1) - max(gx - 4, 0) + 1;
        totv[pp] = (float)(rin * cin);
        l2tv[pp] = __log2f(totv[pp]);

        unsigned a0=0,a1=0,a2=0,a3=0,a4=0,a5=0,a6=0,a7=0;
#pragma unroll
        for (int dx = 0; dx < 9; dx++) {
            uint4 cs = scol[y][xq + dx];
            a0 += cs.x & 0x0F0F0F0Fu; a1 += (cs.x >> 4) & 0x0F0F0F0Fu;
            a2 += cs.y & 0x0F0F0F0Fu; a3 += (cs.y >> 4) & 0x0F0F0F0Fu;
            a4 += cs.z & 0x0F0F0F0Fu; a5 += (cs.z >> 4) & 0x0F0F0F0Fu;
            a6 += cs.w & 0x0F0F0F0Fu; a7 += (cs.w >> 4) & 0x0F0F0F0Fu;
        }
        float S = 0.f;
        unsigned acc[8] = {a0,a1,a2,a3,a4,a5,a6,a7};
#pragma unroll
        for (int k = 0; k < 8; k++) {
            unsigned a = acc[k];
            S += ftab[a & 255u] + ftab[(a >> 8) & 255u]
               + ftab[(a >> 16) & 255u] + ftab[a >> 24];
        }
        ev[pp] = l2tv[pp] - S / totv[pp];        // e2 (base)
    }

    // ---- pass B (rare): rebuild scol from map1, blend ----
    if (differs) {
        __syncthreads();   // everyone done reading pass-A scol
        for (int i = t; i < TILE*REG; i += 256) {
            int y = i / REG, c = i - y*REG;
            unsigned w0=0,w1=0,w2=0,w3=0;
#pragma unroll
            for (int dy = 0; dy < 9; dy++) {
                unsigned bin = sidx1[y + dy][c];
                unsigned inc = 1u << ((bin & 7u) * 4u);
                unsigned sel = bin >> 3;
                w0 += (sel == 0u) ? inc : 0u;
                w1 += (sel == 1u) ? inc : 0u;
                w2 += (sel == 2u) ? inc : 0u;
                w3 += (sel == 3u) ? inc : 0u;
            }
            scol[y][c] = make_uint4(w0, w1, w2, w3);
        }
        __syncthreads();
#pragma unroll
        for (int pp = 0; pp < 4; pp++) {
            int pid = pp * 256 + t;
            int y = pid >> 5, xq = pid & 31;
            unsigned a0=0,a1=0,a2=0,a3=0,a4=0,a5=0,a6=0,a7=0;
#pragma unroll
            for (int dx = 0; dx < 9; dx++) {
                uint4 cs = scol[y][xq + dx];
                a0 += cs.x & 0x0F0F0F0Fu; a1 += (cs.x >> 4) & 0x0F0F0F0Fu;
                a2 += cs.y & 0x0F0F0F0Fu; a3 += (cs.y >> 4) & 0x0F0F0F0Fu;
                a4 += cs.z & 0x0F0F0F0Fu; a5 += (cs.z >> 4) & 0x0F0F0F0Fu;
                a6 += cs.w & 0x0F0F0F0Fu; a7 += (cs.w >> 4) & 0x0F0F0F0Fu;
            }
            float S = 0.f;
            unsigned acc[8] = {a0,a1,a2,a3,a4,a5,a6,a7};
#pragma unroll
            for (int k = 0; k < 8; k++) {
                unsigned a = acc[k];
                S += ftab[a & 255u] + ftab[(a >> 8) & 255u]
                   + ftab[(a >> 16) & 255u] + ftab[a >> 24];
            }
            float e1 = l2tv[pp] - S / totv[pp];
            ev[pp] = ev[pp] + WBLEND * (e1 - ev[pp]);   // e2 + W*(e1-e2)
        }
    }

    // ---- write out + per-batch min/max ----
    float lmn = INFINITY, lmx = -INFINITY;
    float* eb = entbase + ((size_t)(b*NCH + 10)) * HWSZ;
#pragma unroll
    for (int pp = 0; pp < 4; pp++) {
        int pid = pp * 256 + t;
        int y = pid >> 5, xq = pid & 31;
        int gy = y0 + y, gx = x0 + xq;
        eb[gy*WW + gx] = ev[pp];
        lmn = fminf(lmn, ev[pp]); lmx = fmaxf(lmx, ev[pp]);
    }
#pragma unroll
    for (int off = 32; off; off >>= 1) {
        lmn = fminf(lmn, __shfl_xor(lmn, off));
        lmx = fmaxf(lmx, __shfl_xor(lmx, off));
    }
    if ((t & 63) == 0) {
        atomicMin(&mm[(b*NCH + 10)*2    ], encf(lmn));
        atomicMax(&mm[(b*NCH + 10)*2 + 1], encf(lmx));
    }
}

// final: recompute diffs, read raw entropy in-place, normalize all 11 channels
__global__ __launch_bounds__(256) void k_final(const float* __restrict__ x,
                                               const unsigned* __restrict__ mm,
                                               float* out) {
    int b = blockIdx.y;
    const float* xb = x + (size_t)b * 5 * HWSZ;
    float* ob = out + (size_t)b * NCH * HWSZ;
    float mnv[11], dnv[11];
#pragma unroll
    for (int c = 0; c < 11; c++) {
        mnv[c] = decf(mm[(b*NCH + c)*2]);
        dnv[c] = decf(mm[(b*NCH + c)*2 + 1]) - mnv[c] + 1e-6f;
    }
    for (int p = blockIdx.x * blockDim.x + threadIdx.x; p < HWSZ; p += gridDim.x * blockDim.x) {
        float x0 = xb[p], x1 = xb[HWSZ + p], x2 = xb[2*HWSZ + p], x3 = xb[3*HWSZ + p], x4 = xb[4*HWSZ + p];
        float e = ob[(size_t)10*HWSZ + p];
        float d[11] = { x0-x1, x0-x2, x0-x3, x0-x4, x1-x2, x1-x3, x1-x4, x2-x3, x2-x4, x3-x4, e };
#pragma unroll
        for (int c = 0; c < 11; c++) {
            ob[(size_t)c*HWSZ + p] = (d[c] - mnv[c]) / dnv[c];
        }
    }
}

extern "C" void kernel_launch(void* const* d_in, const int* in_sizes, int n_in,
                              void* d_out, int out_size, void* d_ws, size_t ws_size,
                              hipStream_t stream) {
    const float* x = (const float*)d_in[0];
    float* out = (float*)d_out;
    unsigned* mm = (unsigned*)d_ws;                 // 704 B in workspace
    // two bin-index maps (2 MB each) overlaid on d_out start (b0 ch0..ch3),
    // consumed by k_entropy before k_final overwrites them.
    unsigned char* bidx1 = (unsigned char*)d_out;
    unsigned char* bidx2 = (unsigned char*)d_out + (size_t)BATCH * HWSZ;

    k_init<<<1, 256, 0, stream>>>(mm);
    k_minmax<<<dim3(64, BATCH), 256, 0, stream>>>(x, mm);
    k_binidx<<<dim3(128, BATCH), 256, 0, stream>>>(x, mm, bidx1, bidx2);
    k_entropy<<<dim3(WW/TILE, HH/TILE, BATCH), 256, 0, stream>>>(bidx1, bidx2, out, mm);
    k_final<<<dim3(512, BATCH), 256, 0, stream>>>(x, mm, out);
}

// Round 7
// 133.750 us; speedup vs baseline: 1.7994x; 1.6226x over previous
//
#include <hip/hip_runtime.h>

#define BATCH 8
#define NCH 11
#define HH 512
#define WW 512
#define HWSZ (HH*WW)
#define TILE 32
#define REG 40   // TILE + 8 halo
#define WBLEND 0.645f

// ---- monotone float<->uint encoding for atomic min/max (f32) ----
__device__ __forceinline__ unsigned encf(float f) {
    unsigned u = __float_as_uint(f);
    return u ^ ((unsigned)((int)u >> 31) | 0x80000000u);
}
__device__ __forceinline__ float decf(unsigned e) {
    unsigned u = (e & 0x80000000u) ? (e ^ 0x80000000u) : ~e;
    return __uint_as_float(u);
}

// mm layout: [BATCH][NCH][2] u32  (min_enc, max_enc)
__global__ void k_init(unsigned* __restrict__ mm) {
    int i = threadIdx.x;
    if (i < BATCH * NCH) { mm[2*i] = 0xFFFFFFFFu; mm[2*i+1] = 0u; }
}

// per-(b,pair) f32 min/max of the 10 channel diffs — float4, full occupancy,
// block-level reduction, 20 atomics per block.
__global__ __launch_bounds__(256) void k_minmax(const float4* __restrict__ x4,
                                                unsigned* __restrict__ mm) {
    int b = blockIdx.y;
    const float4* xb = x4 + (size_t)b * 5 * (HWSZ/4);
    float mn[10], mx[10];
#pragma unroll
    for (int i = 0; i < 10; i++) { mn[i] = INFINITY; mx[i] = -INFINITY; }

    int p = blockIdx.x * blockDim.x + threadIdx.x;   // exactly HWSZ/4 threads
    float4 v0 = xb[p];
    float4 v1 = xb[(HWSZ/4) + p];
    float4 v2 = xb[2*(HWSZ/4) + p];
    float4 v3 = xb[3*(HWSZ/4) + p];
    float4 v4 = xb[4*(HWSZ/4) + p];
    const float* a0 = &v0.x; const float* a1 = &v1.x; const float* a2 = &v2.x;
    const float* a3 = &v3.x; const float* a4 = &v4.x;
#pragma unroll
    for (int c = 0; c < 4; c++) {
        float x0 = a0[c], x1 = a1[c], x2 = a2[c], x3 = a3[c], x4v = a4[c];
        float d[10] = { x0-x1, x0-x2, x0-x3, x0-x4v, x1-x2, x1-x3, x1-x4v, x2-x3, x2-x4v, x3-x4v };
#pragma unroll
        for (int i = 0; i < 10; i++) { mn[i] = fminf(mn[i], d[i]); mx[i] = fmaxf(mx[i], d[i]); }
    }
#pragma unroll
    for (int i = 0; i < 10; i++) {
#pragma unroll
        for (int off = 32; off; off >>= 1) {
            mn[i] = fminf(mn[i], __shfl_xor(mn[i], off));
            mx[i] = fmaxf(mx[i], __shfl_xor(mx[i], off));
        }
    }
    __shared__ float smn[4][10], smx[4][10];
    int w = threadIdx.x >> 6;
    if ((threadIdx.x & 63) == 0) {
#pragma unroll
        for (int i = 0; i < 10; i++) { smn[w][i] = mn[i]; smx[w][i] = mx[i]; }
    }
    __syncthreads();
    int t = threadIdx.x;
    if (t < 10) {
        float m = fminf(fminf(smn[0][t], smn[1][t]), fminf(smn[2][t], smn[3][t]));
        atomicMin(&mm[(b*NCH + t)*2], encf(m));
    } else if (t < 20) {
        int i = t - 10;
        float M = fmaxf(fmaxf(smx[0][i], smx[1][i]), fmaxf(smx[2][i], smx[3][i]));
        atomicMax(&mm[(b*NCH + i)*2 + 1], encf(M));
    }
}

// Two candidate bin maps from the same f32 diff (float4 in, uchar4 out):
//   map1: all-f32 normalize chain, map2: f64 normalize chain
__global__ __launch_bounds__(256) void k_binidx(const float4* __restrict__ x4,
                                                const unsigned* __restrict__ mm,
                                                uchar4* __restrict__ bidx1,
                                                uchar4* __restrict__ bidx2) {
    int b = blockIdx.y;
    float mnf = decf(mm[(b*NCH + 8)*2]);
    float mxf = decf(mm[(b*NCH + 8)*2 + 1]);
    float denf = mxf - mnf + 1e-6f;
    double mnd = (double)mnf;
    double dend = (double)mxf - (double)mnf + 1e-6;
    const float4* xb = x4 + (size_t)b * 5 * (HWSZ/4);
    uchar4* ib1 = bidx1 + (size_t)b * (HWSZ/4);
    uchar4* ib2 = bidx2 + (size_t)b * (HWSZ/4);
    for (int p = blockIdx.x * blockDim.x + threadIdx.x; p < HWSZ/4; p += gridDim.x * blockDim.x) {
        float4 v2 = xb[2*(HWSZ/4) + p];
        float4 v4 = xb[4*(HWSZ/4) + p];
        const float* c2 = &v2.x; const float* c4 = &v4.x;
        unsigned char q1c[4], q2c[4];
#pragma unroll
        for (int c = 0; c < 4; c++) {
            float d = c2[c] - c4[c];
            float v1f = (d - mnf) / denf;
            q1c[c] = (unsigned char)(int)(v1f * 31.0f);
            double v2d = ((double)d - mnd) / dend;
            q2c[c] = (unsigned char)(int)(v2d * 31.0);
        }
        ib1[p] = make_uchar4(q1c[0], q1c[1], q1c[2], q1c[3]);
        ib2[p] = make_uchar4(q2c[0], q2c[1], q2c[2], q2c[3]);
    }
}

// dual-chain 9x9/32-bin entropy with single shared scol buffer.
// Base pass always uses map2; map1 pass + blend only if the tile differs.
__global__ __launch_bounds__(256) void k_entropy(const unsigned char* __restrict__ bidx1,
                                                 const unsigned char* __restrict__ bidx2,
                                                 float* entbase,
                                                 unsigned* __restrict__ mm) {
    __shared__ unsigned char sidx1[REG][REG];   // 1600 B
    __shared__ unsigned char sidx2[REG][REG];   // 1600 B
    __shared__ uint4 scol[TILE][REG];           // 20480 B (shared by both passes)
    __shared__ float ftab[96];                  // n * log2(n)
    __shared__ int tile_differs;

    int b  = blockIdx.z;
    int y0 = blockIdx.y * TILE, x0 = blockIdx.x * TILE;
    int t  = threadIdx.x;

    if (t == 0) tile_differs = 0;
    if (t < 96) ftab[t] = (t == 0) ? 0.0f : (float)t * __log2f((float)t);
    __syncthreads();

    const unsigned char* ib1 = bidx1 + (size_t)b * HWSZ;
    const unsigned char* ib2 = bidx2 + (size_t)b * HWSZ;
    int mydiff = 0;
    for (int i = t; i < REG*REG; i += 256) {
        int r = i / REG, c = i - r*REG;
        int gy = y0 + r - 4, gx = x0 + c - 4;
        unsigned char v1 = 255, v2 = 255;
        if (gy >= 0 && gy < HH && gx >= 0 && gx < WW) {
            v1 = ib1[gy*WW + gx];
            v2 = ib2[gy*WW + gx];
        }
        sidx1[r][c] = v1;
        sidx2[r][c] = v2;
        mydiff |= (v1 != v2);
    }
    if (mydiff) tile_differs = 1;
    __syncthreads();
    bool differs = (tile_differs != 0);   // block-uniform

    // ---- pass A: column hists + entropy from map2 (base) ----
    for (int i = t; i < TILE*REG; i += 256) {
        int y = i / REG, c = i - y*REG;
        unsigned w0=0,w1=0,w2=0,w3=0;
#pragma unroll
        for (int dy = 0; dy < 9; dy++) {
            unsigned bin = sidx2[y + dy][c];
            unsigned inc = 1u << ((bin & 7u) * 4u);
            unsigned sel = bin >> 3;
            w0 += (sel == 0u) ? inc : 0u;
            w1 += (sel == 1u) ? inc : 0u;
            w2 += (sel == 2u) ? inc : 0u;
            w3 += (sel == 3u) ? inc : 0u;
        }
        scol[y][c] = make_uint4(w0, w1, w2, w3);
    }
    __syncthreads();

    float ev[4];
    float totv[4], l2tv[4];
#pragma unroll
    for (int pp = 0; pp < 4; pp++) {
        int pid = pp * 256 + t;
        int y = pid >> 5, xq = pid & 31;
        int gy = y0 + y, gx = x0 + xq;
        int rin = min(gy + 4, HH - 1) - max(gy - 4, 0) + 1;
        int cin = min(gx + 4, WW - 1) - max(gx - 4, 0) + 1;
        totv[pp] = (float)(rin * cin);
        l2tv[pp] = __log2f(totv[pp]);

        unsigned a0=0,a1=0,a2=0,a3=0,a4=0,a5=0,a6=0,a7=0;
#pragma unroll
        for (int dx = 0; dx < 9; dx++) {
            uint4 cs = scol[y][xq + dx];
            a0 += cs.x & 0x0F0F0F0Fu; a1 += (cs.x >> 4) & 0x0F0F0F0Fu;
            a2 += cs.y & 0x0F0F0F0Fu; a3 += (cs.y >> 4) & 0x0F0F0F0Fu;
            a4 += cs.z & 0x0F0F0F0Fu; a5 += (cs.z >> 4) & 0x0F0F0F0Fu;
            a6 += cs.w & 0x0F0F0F0Fu; a7 += (cs.w >> 4) & 0x0F0F0F0Fu;
        }
        float S = 0.f;
        unsigned acc[8] = {a0,a1,a2,a3,a4,a5,a6,a7};
#pragma unroll
        for (int k = 0; k < 8; k++) {
            unsigned a = acc[k];
            S += ftab[a & 255u] + ftab[(a >> 8) & 255u]
               + ftab[(a >> 16) & 255u] + ftab[a >> 24];
        }
        ev[pp] = l2tv[pp] - S / totv[pp];        // e2 (base)
    }

    // ---- pass B (rare): rebuild scol from map1, blend ----
    if (differs) {
        __syncthreads();   // everyone done reading pass-A scol
        for (int i = t; i < TILE*REG; i += 256) {
            int y = i / REG, c = i - y*REG;
            unsigned w0=0,w1=0,w2=0,w3=0;
#pragma unroll
            for (int dy = 0; dy < 9; dy++) {
                unsigned bin = sidx1[y + dy][c];
                unsigned inc = 1u << ((bin & 7u) * 4u);
                unsigned sel = bin >> 3;
                w0 += (sel == 0u) ? inc : 0u;
                w1 += (sel == 1u) ? inc : 0u;
                w2 += (sel == 2u) ? inc : 0u;
                w3 += (sel == 3u) ? inc : 0u;
            }
            scol[y][c] = make_uint4(w0, w1, w2, w3);
        }
        __syncthreads();
#pragma unroll
        for (int pp = 0; pp < 4; pp++) {
            int pid = pp * 256 + t;
            int y = pid >> 5, xq = pid & 31;
            unsigned a0=0,a1=0,a2=0,a3=0,a4=0,a5=0,a6=0,a7=0;
#pragma unroll
            for (int dx = 0; dx < 9; dx++) {
                uint4 cs = scol[y][xq + dx];
                a0 += cs.x & 0x0F0F0F0Fu; a1 += (cs.x >> 4) & 0x0F0F0F0Fu;
                a2 += cs.y & 0x0F0F0F0Fu; a3 += (cs.y >> 4) & 0x0F0F0F0Fu;
                a4 += cs.z & 0x0F0F0F0Fu; a5 += (cs.z >> 4) & 0x0F0F0F0Fu;
                a6 += cs.w & 0x0F0F0F0Fu; a7 += (cs.w >> 4) & 0x0F0F0F0Fu;
            }
            float S = 0.f;
            unsigned acc[8] = {a0,a1,a2,a3,a4,a5,a6,a7};
#pragma unroll
            for (int k = 0; k < 8; k++) {
                unsigned a = acc[k];
                S += ftab[a & 255u] + ftab[(a >> 8) & 255u]
                   + ftab[(a >> 16) & 255u] + ftab[a >> 24];
            }
            float e1 = l2tv[pp] - S / totv[pp];
            ev[pp] = ev[pp] + WBLEND * (e1 - ev[pp]);   // e2 + W*(e1-e2)
        }
    }

    // ---- write out + per-batch min/max ----
    float lmn = INFINITY, lmx = -INFINITY;
    float* eb = entbase + ((size_t)(b*NCH + 10)) * HWSZ;
#pragma unroll
    for (int pp = 0; pp < 4; pp++) {
        int pid = pp * 256 + t;
        int y = pid >> 5, xq = pid & 31;
        int gy = y0 + y, gx = x0 + xq;
        eb[gy*WW + gx] = ev[pp];
        lmn = fminf(lmn, ev[pp]); lmx = fmaxf(lmx, ev[pp]);
    }
#pragma unroll
    for (int off = 32; off; off >>= 1) {
        lmn = fminf(lmn, __shfl_xor(lmn, off));
        lmx = fmaxf(lmx, __shfl_xor(lmx, off));
    }
    if ((t & 63) == 0) {
        atomicMin(&mm[(b*NCH + 10)*2    ], encf(lmn));
        atomicMax(&mm[(b*NCH + 10)*2 + 1], encf(lmx));
    }
}

// final: recompute diffs (float4), read raw entropy in-place, normalize 11 channels
__global__ __launch_bounds__(256) void k_final(const float4* __restrict__ x4,
                                               const unsigned* __restrict__ mm,
                                               float4* out4) {
    int b = blockIdx.y;
    const float4* xb = x4 + (size_t)b * 5 * (HWSZ/4);
    float4* ob = out4 + (size_t)b * NCH * (HWSZ/4);
    float mnv[11], dnv[11];
#pragma unroll
    for (int c = 0; c < 11; c++) {
        mnv[c] = decf(mm[(b*NCH + c)*2]);
        dnv[c] = decf(mm[(b*NCH + c)*2 + 1]) - mnv[c] + 1e-6f;
    }
    for (int p = blockIdx.x * blockDim.x + threadIdx.x; p < HWSZ/4; p += gridDim.x * blockDim.x) {
        float4 v0 = xb[p];
        float4 v1 = xb[(HWSZ/4) + p];
        float4 v2 = xb[2*(HWSZ/4) + p];
        float4 v3 = xb[3*(HWSZ/4) + p];
        float4 v4 = xb[4*(HWSZ/4) + p];
        float4 ve = ob[(size_t)10*(HWSZ/4) + p];   // raw entropy written by k_entropy
        const float* a0 = &v0.x; const float* a1 = &v1.x; const float* a2 = &v2.x;
        const float* a3 = &v3.x; const float* a4 = &v4.x; const float* ae = &ve.x;
        float4 r[11];
        float* rr = &r[0].x;
#pragma unroll
        for (int c = 0; c < 4; c++) {
            float x0 = a0[c], x1 = a1[c], x2 = a2[c], x3 = a3[c], x4v = a4[c];
            float d[11] = { x0-x1, x0-x2, x0-x3, x0-x4v, x1-x2, x1-x3, x1-x4v,
                            x2-x3, x2-x4v, x3-x4v, ae[c] };
#pragma unroll
            for (int ch = 0; ch < 11; ch++) {
                rr[ch*4 + c] = (d[ch] - mnv[ch]) / dnv[ch];
            }
        }
#pragma unroll
        for (int ch = 0; ch < 11; ch++) {
            ob[(size_t)ch*(HWSZ/4) + p] = r[ch];
        }
    }
}

extern "C" void kernel_launch(void* const* d_in, const int* in_sizes, int n_in,
                              void* d_out, int out_size, void* d_ws, size_t ws_size,
                              hipStream_t stream) {
    const float4* x4 = (const float4*)d_in[0];
    float4* out4 = (float4*)d_out;
    float* out = (float*)d_out;
    unsigned* mm = (unsigned*)d_ws;                 // 704 B in workspace
    // two bin-index maps (2 MB each) overlaid on d_out start (b0 ch0..ch3),
    // consumed by k_entropy before k_final overwrites them.
    unsigned char* bidx1 = (unsigned char*)d_out;
    unsigned char* bidx2 = (unsigned char*)d_out + (size_t)BATCH * HWSZ;

    k_init<<<1, 256, 0, stream>>>(mm);
    k_minmax<<<dim3(HWSZ/4/256, BATCH), 256, 0, stream>>>(x4, mm);
    k_binidx<<<dim3(128, BATCH), 256, 0, stream>>>(x4, mm, (uchar4*)bidx1, (uchar4*)bidx2);
    k_entropy<<<dim3(WW/TILE, HH/TILE, BATCH), 256, 0, stream>>>(bidx1, bidx2, out, mm);
    k_final<<<dim3(128, BATCH), 256, 0, stream>>>(x4, mm, out4);
}

// Round 8
// 131.951 us; speedup vs baseline: 1.8239x; 1.0136x over previous
//
#include <hip/hip_runtime.h>

#define BATCH 8
#define NCH 11
#define HH 512
#define WW 512
#define HWSZ (HH*WW)
#define TILE 32
#define REG 40   // TILE + 8 halo
#define WBLEND 0.645f

// ---- monotone float<->uint encoding for atomic min/max (f32) ----
__device__ __forceinline__ unsigned encf(float f) {
    unsigned u = __float_as_uint(f);
    return u ^ ((unsigned)((int)u >> 31) | 0x80000000u);
}
__device__ __forceinline__ float decf(unsigned e) {
    unsigned u = (e & 0x80000000u) ? (e ^ 0x80000000u) : ~e;
    return __uint_as_float(u);
}

// ws: mm = [BATCH][NCH][2] u32 (704 B) @0; tileflag = [BATCH][16][16] u8 (2048 B) @704
__global__ void k_init(unsigned* __restrict__ mm, unsigned long long* __restrict__ fl) {
    int i = threadIdx.x;
    if (i < BATCH * NCH) { mm[2*i] = 0xFFFFFFFFu; mm[2*i+1] = 0u; }
    fl[i] = 0ULL;   // 256 * 8 = 2048 B of flags
}

// per-(b,pair) f32 min/max of the 10 channel diffs — float4, full occupancy
__global__ __launch_bounds__(256) void k_minmax(const float4* __restrict__ x4,
                                                unsigned* __restrict__ mm) {
    int b = blockIdx.y;
    const float4* xb = x4 + (size_t)b * 5 * (HWSZ/4);
    float mn[10], mx[10];
#pragma unroll
    for (int i = 0; i < 10; i++) { mn[i] = INFINITY; mx[i] = -INFINITY; }

    int p = blockIdx.x * blockDim.x + threadIdx.x;   // exactly HWSZ/4 threads
    float4 v0 = xb[p];
    float4 v1 = xb[(HWSZ/4) + p];
    float4 v2 = xb[2*(HWSZ/4) + p];
    float4 v3 = xb[3*(HWSZ/4) + p];
    float4 v4 = xb[4*(HWSZ/4) + p];
    const float* a0 = &v0.x; const float* a1 = &v1.x; const float* a2 = &v2.x;
    const float* a3 = &v3.x; const float* a4 = &v4.x;
#pragma unroll
    for (int c = 0; c < 4; c++) {
        float x0 = a0[c], x1 = a1[c], x2 = a2[c], x3 = a3[c], x4v = a4[c];
        float d[10] = { x0-x1, x0-x2, x0-x3, x0-x4v, x1-x2, x1-x3, x1-x4v, x2-x3, x2-x4v, x3-x4v };
#pragma unroll
        for (int i = 0; i < 10; i++) { mn[i] = fminf(mn[i], d[i]); mx[i] = fmaxf(mx[i], d[i]); }
    }
#pragma unroll
    for (int i = 0; i < 10; i++) {
#pragma unroll
        for (int off = 32; off; off >>= 1) {
            mn[i] = fminf(mn[i], __shfl_xor(mn[i], off));
            mx[i] = fmaxf(mx[i], __shfl_xor(mx[i], off));
        }
    }
    __shared__ float smn[4][10], smx[4][10];
    int w = threadIdx.x >> 6;
    if ((threadIdx.x & 63) == 0) {
#pragma unroll
        for (int i = 0; i < 10; i++) { smn[w][i] = mn[i]; smx[w][i] = mx[i]; }
    }
    __syncthreads();
    int t = threadIdx.x;
    if (t < 10) {
        float m = fminf(fminf(smn[0][t], smn[1][t]), fminf(smn[2][t], smn[3][t]));
        atomicMin(&mm[(b*NCH + t)*2], encf(m));
    } else if (t < 20) {
        int i = t - 10;
        float M = fmaxf(fmaxf(smx[0][i], smx[1][i]), fmaxf(smx[2][i], smx[3][i]));
        atomicMax(&mm[(b*NCH + i)*2 + 1], encf(M));
    }
}

// Two candidate bin maps (f32 chain / f64 chain) + per-tile diff flags.
// A diff pixel marks every tile whose 40x40 halo region contains it.
__global__ __launch_bounds__(256) void k_binidx(const float4* __restrict__ x4,
                                                const unsigned* __restrict__ mm,
                                                uchar4* __restrict__ bidx1,
                                                uchar4* __restrict__ bidx2,
                                                unsigned char* __restrict__ tileflag) {
    int b = blockIdx.y;
    float mnf = decf(mm[(b*NCH + 8)*2]);
    float mxf = decf(mm[(b*NCH + 8)*2 + 1]);
    float denf = mxf - mnf + 1e-6f;
    double mnd = (double)mnf;
    double dend = (double)mxf - (double)mnf + 1e-6;
    const float4* xb = x4 + (size_t)b * 5 * (HWSZ/4);
    uchar4* ib1 = bidx1 + (size_t)b * (HWSZ/4);
    uchar4* ib2 = bidx2 + (size_t)b * (HWSZ/4);
    for (int p = blockIdx.x * blockDim.x + threadIdx.x; p < HWSZ/4; p += gridDim.x * blockDim.x) {
        float4 v2 = xb[2*(HWSZ/4) + p];
        float4 v4 = xb[4*(HWSZ/4) + p];
        const float* c2 = &v2.x; const float* c4 = &v4.x;
        unsigned char q1c[4], q2c[4];
#pragma unroll
        for (int c = 0; c < 4; c++) {
            float d = c2[c] - c4[c];
            float v1f = (d - mnf) / denf;
            q1c[c] = (unsigned char)(int)(v1f * 31.0f);
            double v2d = ((double)d - mnd) / dend;
            q2c[c] = (unsigned char)(int)(v2d * 31.0);
        }
        ib1[p] = make_uchar4(q1c[0], q1c[1], q1c[2], q1c[3]);
        ib2[p] = make_uchar4(q2c[0], q2c[1], q2c[2], q2c[3]);
#pragma unroll
        for (int c = 0; c < 4; c++) {
            if (q1c[c] != q2c[c]) {                      // rare
                int pix = p*4 + c;
                int gy = pix >> 9, gx = pix & (WW-1);
                int tylo = max(0, (gy-4) >> 5), tyhi = min(15, (gy+4) >> 5);
                int txlo = max(0, (gx-4) >> 5), txhi = min(15, (gx+4) >> 5);
                for (int ty = tylo; ty <= tyhi; ty++)
                    for (int tx = txlo; tx <= txhi; tx++)
                        tileflag[(b*16 + ty)*16 + tx] = 1;  // idempotent store
            }
        }
    }
}

// stage one 40x40 bin-map tile into LDS (dword fast path for interior tiles)
__device__ __forceinline__ void stage_map(const unsigned char* __restrict__ ib,
                                          unsigned* __restrict__ sidxw,
                                          int y0, int x0, int t, bool interior) {
    if (interior) {
        const unsigned char* src = ib + (size_t)(y0-4)*WW + (x0-4);   // 4-aligned
        for (int i = t; i < 400; i += 256) {
            int r = i / 10, c4 = i - r*10;
            sidxw[r*10 + c4] = *(const unsigned*)(src + (size_t)r*WW + c4*4);
        }
    } else {
        unsigned char* sx = (unsigned char*)sidxw;
        for (int i = t; i < REG*REG; i += 256) {
            int r = i / REG, c = i - r*REG;
            int gy = y0 + r - 4, gx = x0 + c - 4;
            unsigned char v = 255;
            if (gy >= 0 && gy < HH && gx >= 0 && gx < WW) v = ib[gy*WW + gx];
            sx[r*REG + c] = v;
        }
    }
}

// build packed column hists (32 bins x 4-bit) from staged bytes
__device__ __forceinline__ void build_scol(const unsigned char* __restrict__ sx,
                                           uint4 (*scol)[REG], int t) {
    for (int i = t; i < TILE*REG; i += 256) {
        int y = i / REG, c = i - y*REG;
        unsigned w0=0,w1=0,w2=0,w3=0;
#pragma unroll
        for (int dy = 0; dy < 9; dy++) {
            unsigned bin = sx[(y + dy)*REG + c];
            unsigned inc = 1u << ((bin & 7u) * 4u);
            unsigned sel = bin >> 3;            // >=4 for OOB sentinel
            w0 += (sel == 0u) ? inc : 0u;
            w1 += (sel == 1u) ? inc : 0u;
            w2 += (sel == 2u) ? inc : 0u;
            w3 += (sel == 3u) ? inc : 0u;
        }
        scol[y][c] = make_uint4(w0, w1, w2, w3);
    }
}

#define MLO 0x0F0F0F0Fu
#define ACCQ(Q) { a0 += (Q).x & MLO; a1 += ((Q).x >> 4) & MLO; \
                  a2 += (Q).y & MLO; a3 += ((Q).y >> 4) & MLO; \
                  a4 += (Q).z & MLO; a5 += ((Q).z >> 4) & MLO; \
                  a6 += (Q).w & MLO; a7 += ((Q).w >> 4) & MLO; }

// entropy for one pixel from 9 packed column hists (preloaded for MLP)
__device__ __forceinline__ float ent_eval(const uint4 (*scol)[REG], int y, int xq,
                                          float l2t, float tot, const float* __restrict__ ftab) {
    uint4 q0 = scol[y][xq+0], q1 = scol[y][xq+1], q2 = scol[y][xq+2],
          q3 = scol[y][xq+3], q4 = scol[y][xq+4], q5 = scol[y][xq+5],
          q6 = scol[y][xq+6], q7 = scol[y][xq+7], q8 = scol[y][xq+8];
    unsigned a0=0,a1=0,a2=0,a3=0,a4=0,a5=0,a6=0,a7=0;
    ACCQ(q0) ACCQ(q1) ACCQ(q2) ACCQ(q3) ACCQ(q4) ACCQ(q5) ACCQ(q6) ACCQ(q7) ACCQ(q8)
    float S = 0.f;
    unsigned acc[8] = {a0,a1,a2,a3,a4,a5,a6,a7};
#pragma unroll
    for (int k = 0; k < 8; k++) {
        unsigned a = acc[k];
        S += ftab[a & 255u] + ftab[(a >> 8) & 255u]
           + ftab[(a >> 16) & 255u] + ftab[a >> 24];
    }
    return l2t - S / tot;
}

// dual-chain 9x9/32-bin entropy; map1 staged+evaluated only when the tile flag says so
__global__ __launch_bounds__(256, 6) void k_entropy(const unsigned char* __restrict__ bidx1,
                                                    const unsigned char* __restrict__ bidx2,
                                                    const unsigned char* __restrict__ tileflag,
                                                    float* entbase,
                                                    unsigned* __restrict__ mm) {
    __shared__ unsigned sidxw[REG*REG/4];       // 1600 B staged bin bytes (one map at a time)
    __shared__ uint4 scol[TILE][REG];           // 20480 B packed column hists
    __shared__ float ftab[96];                  // n * log2(n)

    int b  = blockIdx.z;
    int y0 = blockIdx.y * TILE, x0 = blockIdx.x * TILE;
    int t  = threadIdx.x;
    bool interior = (blockIdx.x >= 1 && blockIdx.x <= 14 && blockIdx.y >= 1 && blockIdx.y <= 14);
    bool differs = (tileflag[(b*16 + blockIdx.y)*16 + blockIdx.x] != 0);  // block-uniform

    if (t < 96) ftab[t] = (t == 0) ? 0.0f : (float)t * __log2f((float)t);

    const unsigned char* ib1 = bidx1 + (size_t)b * HWSZ;
    const unsigned char* ib2 = bidx2 + (size_t)b * HWSZ;
    const unsigned char* sx = (const unsigned char*)sidxw;

    stage_map(ib2, sidxw, y0, x0, t, interior);
    __syncthreads();
    build_scol(sx, scol, t);
    __syncthreads();

    float ev[4], totv[4], l2tv[4];
#pragma unroll
    for (int pp = 0; pp < 4; pp++) {
        int pid = pp * 256 + t;
        int y = pid >> 5, xq = pid & 31;
        int gy = y0 + y, gx = x0 + xq;
        int rin = min(gy + 4, HH - 1) - max(gy - 4, 0) + 1;
        int cin = min(gx + 4, WW - 1) - max(gx - 4, 0) + 1;
        totv[pp] = (float)(rin * cin);
        l2tv[pp] = __log2f(totv[pp]);
        ev[pp] = ent_eval(scol, y, xq, l2tv[pp], totv[pp], ftab);   // e2 (base)
    }

    if (differs) {
        // sidx buffer is dead after scol was built -> restage with map1 (overlaps pass-A compute)
        stage_map(ib1, sidxw, y0, x0, t, interior);
        __syncthreads();   // pass-A scol reads done + map1 staged
        build_scol(sx, scol, t);
        __syncthreads();
#pragma unroll
        for (int pp = 0; pp < 4; pp++) {
            int pid = pp * 256 + t;
            int y = pid >> 5, xq = pid & 31;
            float e1 = ent_eval(scol, y, xq, l2tv[pp], totv[pp], ftab);
            ev[pp] = ev[pp] + WBLEND * (e1 - ev[pp]);   // e2 + W*(e1-e2)
        }
    }

    float lmn = INFINITY, lmx = -INFINITY;
    float* eb = entbase + ((size_t)(b*NCH + 10)) * HWSZ;
#pragma unroll
    for (int pp = 0; pp < 4; pp++) {
        int pid = pp * 256 + t;
        int y = pid >> 5, xq = pid & 31;
        int gy = y0 + y, gx = x0 + xq;
        eb[gy*WW + gx] = ev[pp];
        lmn = fminf(lmn, ev[pp]); lmx = fmaxf(lmx, ev[pp]);
    }
#pragma unroll
    for (int off = 32; off; off >>= 1) {
        lmn = fminf(lmn, __shfl_xor(lmn, off));
        lmx = fmaxf(lmx, __shfl_xor(lmx, off));
    }
    if ((t & 63) == 0) {
        atomicMin(&mm[(b*NCH + 10)*2    ], encf(lmn));
        atomicMax(&mm[(b*NCH + 10)*2 + 1], encf(lmx));
    }
}

// final: recompute diffs (float4), read raw entropy in-place, normalize 11 channels
__global__ __launch_bounds__(256) void k_final(const float4* __restrict__ x4,
                                               const unsigned* __restrict__ mm,
                                               float4* out4) {
    int b = blockIdx.y;
    const float4* xb = x4 + (size_t)b * 5 * (HWSZ/4);
    float4* ob = out4 + (size_t)b * NCH * (HWSZ/4);
    float mnv[11], dnv[11];
#pragma unroll
    for (int c = 0; c < 11; c++) {
        mnv[c] = decf(mm[(b*NCH + c)*2]);
        dnv[c] = decf(mm[(b*NCH + c)*2 + 1]) - mnv[c] + 1e-6f;
    }
    for (int p = blockIdx.x * blockDim.x + threadIdx.x; p < HWSZ/4; p += gridDim.x * blockDim.x) {
        float4 v0 = xb[p];
        float4 v1 = xb[(HWSZ/4) + p];
        float4 v2 = xb[2*(HWSZ/4) + p];
        float4 v3 = xb[3*(HWSZ/4) + p];
        float4 v4 = xb[4*(HWSZ/4) + p];
        float4 ve = ob[(size_t)10*(HWSZ/4) + p];   // raw entropy from k_entropy
        const float* a0 = &v0.x; const float* a1 = &v1.x; const float* a2 = &v2.x;
        const float* a3 = &v3.x; const float* a4 = &v4.x; const float* ae = &ve.x;
        float4 r[11];
        float* rr = &r[0].x;
#pragma unroll
        for (int c = 0; c < 4; c++) {
            float x0 = a0[c], x1 = a1[c], x2 = a2[c], x3 = a3[c], x4v = a4[c];
            float d[11] = { x0-x1, x0-x2, x0-x3, x0-x4v, x1-x2, x1-x3, x1-x4v,
                            x2-x3, x2-x4v, x3-x4v, ae[c] };
#pragma unroll
            for (int ch = 0; ch < 11; ch++) {
                rr[ch*4 + c] = (d[ch] - mnv[ch]) / dnv[ch];
            }
        }
#pragma unroll
        for (int ch = 0; ch < 11; ch++) {
            ob[(size_t)ch*(HWSZ/4) + p] = r[ch];
        }
    }
}

extern "C" void kernel_launch(void* const* d_in, const int* in_sizes, int n_in,
                              void* d_out, int out_size, void* d_ws, size_t ws_size,
                              hipStream_t stream) {
    const float4* x4 = (const float4*)d_in[0];
    float4* out4 = (float4*)d_out;
    float* out = (float*)d_out;
    unsigned* mm = (unsigned*)d_ws;                            // 704 B
    unsigned char* tileflag = (unsigned char*)d_ws + 704;      // 2048 B
    // two bin-index maps (2 MB each) overlaid on d_out start (b0 ch0..ch3),
    // consumed by k_entropy before k_final overwrites them.
    unsigned char* bidx1 = (unsigned char*)d_out;
    unsigned char* bidx2 = (unsigned char*)d_out + (size_t)BATCH * HWSZ;

    k_init<<<1, 256, 0, stream>>>(mm, (unsigned long long*)tileflag);
    k_minmax<<<dim3(HWSZ/4/256, BATCH), 256, 0, stream>>>(x4, mm);
    k_binidx<<<dim3(256, BATCH), 256, 0, stream>>>(x4, mm, (uchar4*)bidx1, (uchar4*)bidx2, tileflag);
    k_entropy<<<dim3(WW/TILE, HH/TILE, BATCH), 256, 0, stream>>>(bidx1, bidx2, tileflag, out, mm);
    k_final<<<dim3(128, BATCH), 256, 0, stream>>>(x4, mm, out4);
}